// Round 2
// baseline (716.368 us; speedup 1.0000x reference)
//
#include <hip/hip_runtime.h>
#include <stdint.h>
#include <math.h>

#define B 64
#define P 8732
#define C 81
#define O 16
#define THRESH 0.5f
#define NEGPOS 3
#define VAR0 0.1f
#define VAR1 0.2f

// loss_k tiling: 4 waves/block, 16-lane groups, TWO rows per group per body
#define ITER 4
#define ROWS_PER_WAVE (8 * ITER)           // 32
#define ROWS_PER_BLOCK (4 * ROWS_PER_WAVE) // 128
#define NBLK ((P + ROWS_PER_BLOCK - 1) / ROWS_PER_BLOCK)  // 69 blocks per batch

// Mining tile: 256 threads, ceil(P/256) = 35 values per thread
#define MJ 35

// ---------------------------------------------------------------------------
// K1: best prior per (b,o) + accumulator/counter init. One wave per (b,o),
// 256 blocks x 256 threads. Packed running-max key -> ties resolve to the
// SMALLEST p (argmax first-occurrence).
// ---------------------------------------------------------------------------
__global__ __launch_bounds__(256) void bp_k(const float* __restrict__ dbox,
                                            const float* __restrict__ truths,
                                            int* __restrict__ forced_p,
                                            int* __restrict__ num_pos,
                                            float* __restrict__ possum,
                                            float* __restrict__ lossl,
                                            float* __restrict__ acc,
                                            int* __restrict__ done,
                                            int* __restrict__ done_b) {
    const int tid = threadIdx.x;
    if (blockIdx.x == 0) {                 // init for the fused kernel (stream order)
        if (tid < B) { num_pos[tid] = 0; possum[tid] = 0.f; lossl[tid] = 0.f; done_b[tid] = 0; }
        if (tid == B) { acc[0] = 0.f; acc[1] = 0.f; }
        if (tid == B + 1) { *done = 0; }
    }
    const int lane = tid & 63;
    const int gw = blockIdx.x * 4 + (tid >> 6);     // 0..1023 = (b,o) pair
    const int b = gw >> 4, o = gw & 15;
    const float4 t = *(const float4*)(truths + (size_t)(b * O + o) * 4);
    const float ta = (t.z - t.x) * (t.w - t.y);

    unsigned long long best = 0ull;
    for (int p0 = lane; p0 < P; p0 += 256) {
#pragma unroll
        for (int u = 0; u < 4; ++u) {
            const int p = p0 + 64 * u;
            if (p < P) {
                const float4 db = *(const float4*)(dbox + (size_t)p * 4);
                const float px0 = db.x - db.z * 0.5f, py0 = db.y - db.w * 0.5f;
                const float px1 = db.x + db.z * 0.5f, py1 = db.y + db.w * 0.5f;
                const float parea = (px1 - px0) * (py1 - py0);
                float ix = fminf(t.z, px1) - fmaxf(t.x, px0);
                float iy = fminf(t.w, py1) - fmaxf(t.y, py0);
                ix = fmaxf(ix, 0.f); iy = fmaxf(iy, 0.f);
                const float inter = ix * iy;
                const float ov = inter / (ta + parea - inter);
                const unsigned long long key =
                    ((unsigned long long)__float_as_uint(ov) << 32) |
                    (unsigned long long)(0xFFFFFFFFu - (unsigned)p);
                if (key > best) best = key;
            }
        }
    }
    for (int off = 32; off; off >>= 1) {
        const unsigned long long o2 = __shfl_xor(best, off);
        if (o2 > best) best = o2;
    }
    if (lane == 0)
        forced_p[b * O + o] = (int)(0xFFFFFFFFu - (unsigned)(best & 0xFFFFFFFFull));
}

// ---------------------------------------------------------------------------
// K2: fused match + one-pass CE + smooth-L1 + PER-BATCH HARD-NEGATIVE MINING.
// Loss body identical to the verified round-1 version. New: the last block to
// finish batch b (device-scope done_b counter) mines b's top-k negatives in
// registers (MJ=35/thread; regs reused from the then-dead loss phase), then
// the globally-last block finalizes the two outputs. Mining for batch b
// overlaps loss work of other batches -> mine_k's serial tail + launch gap
// are removed from the critical path. Cross-block data flows use agent-scope
// atomics/fences (same mechanism the previous mine_k finalize proved out).
// ---------------------------------------------------------------------------
__global__ __launch_bounds__(256) void loss_mine_k(
        const float* __restrict__ loc_data,
        const float* __restrict__ conf_data,
        const float* __restrict__ dbox,
        const float* __restrict__ truths,
        const int* __restrict__ labels,
        const int* __restrict__ forced_p,
        float* __restrict__ negce,
        int* __restrict__ num_pos, float* __restrict__ possum,
        float* __restrict__ lossl,
        float* __restrict__ acc, int* __restrict__ done,
        int* __restrict__ done_b,
        float* __restrict__ out) {
    const int b = blockIdx.y;
    const int tid = threadIdx.x;
    const int lane = tid & 63;
    const int wid = tid >> 6;             // 0..3
    const int sub = lane & 15;
    const int gbase = lane & 48;          // 16*group

    __shared__ float s_truth[O * 4];
    __shared__ float s_l, s_p;
    __shared__ int s_n;
    __shared__ int s_mine;
    if (tid < O * 4) s_truth[tid] = truths[b * O * 4 + tid];
    if (tid == 0) { s_l = 0.f; s_p = 0.f; s_n = 0; }

    // per-lane registers: truth o=sub, forced prior o=sub, label o=sub
    const float4 tt = *(const float4*)(truths + (size_t)(b * O + sub) * 4);
    const int f_reg = forced_p[b * O + sub];
    const int lab_reg = labels[b * O + sub];
    const float tarea = (tt.z - tt.x) * (tt.w - tt.y);
    __syncthreads();

    float l_acc = 0.f;      // smooth-L1 partials
    float p_acc = 0.f;      // positive-CE partial
    int n_acc = 0;          // positive count partial

    const int wbase = blockIdx.x * ROWS_PER_BLOCK + wid * ROWS_PER_WAVE;

    for (int r = 0; r < ITER; ++r) {
        const int pA = wbase + 8 * r + (gbase >> 4);
        const int pB = pA + 4;
        const bool actA = (pA < P), actB = (pB < P);
        const int dA = actA ? pA : P - 1;
        const int dB = actB ? pB : P - 1;
        const size_t rowA = (size_t)b * P + dA;
        const size_t rowB = (size_t)b * P + dB;

        // ---- issue ALL loads for both rows up front (wide)
        const float* rpA = conf_data + rowA * C;
        const float* rpB = conf_data + rowB * C;
        const float4 qA = *(const float4*)(rpA + 4 * sub);   // floats 0..63
        const float4 qB = *(const float4*)(rpB + 4 * sub);
        const float eA = rpA[64 + sub];                      // floats 64..79
        const float eB = rpB[64 + sub];
        const float e80A = rpA[80];                          // broadcast
        const float e80B = rpB[80];
        const float4 dbA = *(const float4*)(dbox + (size_t)dA * 4);
        const float4 dbB = *(const float4*)(dbox + (size_t)dB * 4);

        // ---- IoU + 16-lane argmax for A and B (chains interleave)
        float ovA, ovB;
        int tiA = sub, tiB = sub;
        {
            const float pax0 = dbA.x - dbA.z * 0.5f, pay0 = dbA.y - dbA.w * 0.5f;
            const float pax1 = dbA.x + dbA.z * 0.5f, pay1 = dbA.y + dbA.w * 0.5f;
            const float pareaA = (pax1 - pax0) * (pay1 - pay0);
            float ixA = fminf(tt.z, pax1) - fmaxf(tt.x, pax0);
            float iyA = fminf(tt.w, pay1) - fmaxf(tt.y, pay0);
            ixA = fmaxf(ixA, 0.f); iyA = fmaxf(iyA, 0.f);
            const float interA = ixA * iyA;
            ovA = interA / (tarea + pareaA - interA);

            const float pbx0 = dbB.x - dbB.z * 0.5f, pby0 = dbB.y - dbB.w * 0.5f;
            const float pbx1 = dbB.x + dbB.z * 0.5f, pby1 = dbB.y + dbB.w * 0.5f;
            const float pareaB = (pbx1 - pbx0) * (pby1 - pby0);
            float ixB = fminf(tt.z, pbx1) - fmaxf(tt.x, pbx0);
            float iyB = fminf(tt.w, pby1) - fmaxf(tt.y, pby0);
            ixB = fmaxf(ixB, 0.f); iyB = fmaxf(iyB, 0.f);
            const float interB = ixB * iyB;
            ovB = interB / (tarea + pareaB - interB);
        }
        for (int off = 8; off; off >>= 1) {
            const float oA = __shfl_xor(ovA, off);
            const int iA = __shfl_xor(tiA, off);
            const float oB = __shfl_xor(ovB, off);
            const int iB = __shfl_xor(tiB, off);
            if (oA > ovA || (oA == ovA && iA < tiA)) { ovA = oA; tiA = iA; }
            if (oB > ovB || (oB == ovB && iB < tiB)) { ovB = oB; tiB = iB; }
        }
        // ---- forced override via ballot (ascending o => highest set bit wins)
        const unsigned long long balA = __ballot(f_reg == pA);
        const unsigned long long balB = __ballot(f_reg == pB);
        const unsigned mA = (unsigned)(balA >> gbase) & 0xFFFFu;
        const unsigned mB = (unsigned)(balB >> gbase) & 0xFFFFu;
        const bool fA = (mA != 0), fB = (mB != 0);
        if (fA) tiA = 31 - __clz(mA);
        if (fB) tiB = 31 - __clz(mB);
        const int labA = __shfl(lab_reg, gbase | tiA);
        const int labB = __shfl(lab_reg, gbase | tiB);
        const int confA = (fA || ovA >= THRESH) ? (labA + 1) : 0;
        const int confB = (fB || ovB >= THRESH) ? (labB + 1) : 0;
        const bool posA = confA > 0, posB = confB > 0;

        // ---- one-pass CE, both rows interleaved
        float sA = __expf(qA.x) + __expf(qA.y) + __expf(qA.z) + __expf(qA.w) + __expf(eA);
        float sB = __expf(qB.x) + __expf(qB.y) + __expf(qB.z) + __expf(qB.w) + __expf(eB);
        for (int off = 8; off; off >>= 1) {
            sA += __shfl_xor(sA, off);
            sB += __shfl_xor(sB, off);
        }
        sA += __expf(e80A);
        sB += __expf(e80B);

        // picked logit: fetch from holder lane with one shuffle
        const float selA = (confA < 64)
            ? ((confA & 2) ? ((confA & 1) ? qA.w : qA.z) : ((confA & 1) ? qA.y : qA.x))
            : eA;
        const float selB = (confB < 64)
            ? ((confB & 2) ? ((confB & 1) ? qB.w : qB.z) : ((confB & 1) ? qB.y : qB.x))
            : eB;
        const int hA = (confA < 64) ? (confA >> 2) : (confA & 15);
        const int hB = (confB < 64) ? (confB >> 2) : (confB & 15);
        float pkA = __shfl(selA, gbase | hA);
        float pkB = __shfl(selB, gbase | hB);
        if (confA == 80) pkA = e80A;
        if (confB == 80) pkB = e80B;

        const float cevA = __logf(sA) - pkA;
        const float cevB = __logf(sB) - pkB;

        if (actA && sub == 0) {
            __hip_atomic_store(&negce[rowA], posA ? 0.f : cevA,
                               __ATOMIC_RELAXED, __HIP_MEMORY_SCOPE_AGENT);
            if (posA) { p_acc += cevA; n_acc++; }
        }
        if (actB && sub == 0) {
            __hip_atomic_store(&negce[rowB], posB ? 0.f : cevB,
                               __ATOMIC_RELAXED, __HIP_MEMORY_SCOPE_AGENT);
            if (posB) { p_acc += cevB; n_acc++; }
        }
        // ---- smooth-L1: lanes sub<4 handle one component each
        if (actA && posA && sub < 4) {
            const float mx0 = s_truth[tiA * 4 + 0], my0 = s_truth[tiA * 4 + 1];
            const float mx1 = s_truth[tiA * 4 + 2], my1 = s_truth[tiA * 4 + 3];
            float tgt;
            if (sub == 0)      tgt = ((mx0 + mx1) * 0.5f - dbA.x) / (VAR0 * dbA.z);
            else if (sub == 1) tgt = ((my0 + my1) * 0.5f - dbA.y) / (VAR0 * dbA.w);
            else if (sub == 2) tgt = logf((mx1 - mx0) / dbA.z) / VAR1;
            else               tgt = logf((my1 - my0) / dbA.w) / VAR1;
            const float d = fabsf(loc_data[rowA * 4 + sub] - tgt);
            l_acc += (d < 1.f) ? 0.5f * d * d : d - 0.5f;
        }
        if (actB && posB && sub < 4) {
            const float mx0 = s_truth[tiB * 4 + 0], my0 = s_truth[tiB * 4 + 1];
            const float mx1 = s_truth[tiB * 4 + 2], my1 = s_truth[tiB * 4 + 3];
            float tgt;
            if (sub == 0)      tgt = ((mx0 + mx1) * 0.5f - dbB.x) / (VAR0 * dbB.z);
            else if (sub == 1) tgt = ((my0 + my1) * 0.5f - dbB.y) / (VAR0 * dbB.w);
            else if (sub == 2) tgt = logf((mx1 - mx0) / dbB.z) / VAR1;
            else               tgt = logf((my1 - my0) / dbB.w) / VAR1;
            const float d = fabsf(loc_data[rowB * 4 + sub] - tgt);
            l_acc += (d < 1.f) ? 0.5f * d * d : d - 0.5f;
        }
    }
    // wave reduction of partials, then block, then global
    for (int off = 32; off; off >>= 1) {
        l_acc += __shfl_xor(l_acc, off);
        p_acc += __shfl_xor(p_acc, off);
        n_acc += __shfl_xor(n_acc, off);
    }
    if (lane == 0) {
        atomicAdd(&s_l, l_acc);
        atomicAdd(&s_p, p_acc);
        atomicAdd(&s_n, n_acc);
    }
    __syncthreads();
    if (tid == 0) {
        atomicAdd(&lossl[b], s_l);
        atomicAdd(&possum[b], s_p);
        atomicAdd(&num_pos[b], s_n);
        __threadfence();                   // release: negce + per-b atomics visible
        const int prev = __hip_atomic_fetch_add(&done_b[b], 1,
                             __ATOMIC_ACQ_REL, __HIP_MEMORY_SCOPE_AGENT);
        s_mine = (prev == NBLK - 1) ? 1 : 0;
    }
    __syncthreads();

    // =======================================================================
    // Mining phase: only the last-finishing block of batch b executes this.
    // Loss-phase registers are dead here -> v[MJ] reuses them (no VGPR cost).
    // =======================================================================
    if (s_mine) {
        if (tid == 0) __threadfence();     // acquire for negce plain-path caches
        __syncthreads();
        const float* xb = negce + (size_t)b * P;
        float v[MJ];
#pragma unroll
        for (int j = 0; j < MJ; ++j) {
            const int i = tid + j * 256;
            v[j] = (i < P)
                 ? __hip_atomic_load(&xb[i], __ATOMIC_RELAXED, __HIP_MEMORY_SCOPE_AGENT)
                 : -1.0f;
        }
        int k = __hip_atomic_load(&num_pos[b], __ATOMIC_RELAXED,
                                  __HIP_MEMORY_SCOPE_AGENT) * NEGPOS;
        if (k > P) k = P;

        __shared__ int wred[2][4];
        __shared__ float wsumf[4];
        __shared__ int wcnt[4];
        float S = 0.f;
        if (k > 0) {
            unsigned lo = 0u, hi = 0x7F800000u;
            int parity = 0;
            while (lo < hi) {
                const unsigned mid = lo + ((hi - lo) >> 1);
                const float t = __uint_as_float(mid);
                int cnt = 0;
#pragma unroll
                for (int j = 0; j < MJ; ++j) cnt += (v[j] > t) ? 1 : 0;
                for (int off = 32; off; off >>= 1) cnt += __shfl_xor(cnt, off);
                if (lane == 0) wred[parity][wid] = cnt;
                __syncthreads();
                int total = 0;
#pragma unroll
                for (int w = 0; w < 4; ++w) total += wred[parity][w];
                if (total < k) hi = mid; else lo = mid + 1;
                parity ^= 1;
            }
            const float t = __uint_as_float(lo);   // k-th largest
            float sum = 0.f;
            int cnt = 0;
#pragma unroll
            for (int j = 0; j < MJ; ++j) {
                if (v[j] > t) { sum += v[j]; cnt++; }
            }
            for (int off = 32; off; off >>= 1) {
                sum += __shfl_xor(sum, off);
                cnt += __shfl_xor(cnt, off);
            }
            if (lane == 0) { wsumf[wid] = sum; wcnt[wid] = cnt; }
            __syncthreads();
            if (tid == 0) {
                float ts = 0.f; int tc = 0;
#pragma unroll
                for (int w = 0; w < 4; ++w) { ts += wsumf[w]; tc += wcnt[w]; }
                S = ts + (float)(k - tc) * t;
            }
        }
        if (tid == 0) {
            const float psum = __hip_atomic_load(&possum[b], __ATOMIC_RELAXED,
                                                 __HIP_MEMORY_SCOPE_AGENT);
            atomicAdd(&acc[1], psum + S);
            __threadfence();
            const int prev2 = atomicAdd(done, 1);
            if (prev2 == B - 1) {               // globally last block finalizes
                __threadfence();
                float N = 0.f, L = 0.f;
                for (int i = 0; i < B; ++i) {
                    N += (float)__hip_atomic_load(&num_pos[i], __ATOMIC_RELAXED,
                                                  __HIP_MEMORY_SCOPE_AGENT);
                    L += __hip_atomic_load(&lossl[i], __ATOMIC_RELAXED,
                                           __HIP_MEMORY_SCOPE_AGENT);
                }
                const float cval = atomicAdd(&acc[1], 0.0f);  // coherent read
                out[0] = L / N;
                out[1] = cval / N;
            }
        }
    }
}

extern "C" void kernel_launch(void* const* d_in, const int* in_sizes, int n_in,
                              void* d_out, int out_size, void* d_ws, size_t ws_size,
                              hipStream_t stream) {
    (void)in_sizes; (void)n_in; (void)out_size; (void)ws_size;
    const float* loc_data  = (const float*)d_in[0];   // [B,P,4]
    const float* conf_data = (const float*)d_in[1];   // [B,P,C]
    const float* dbox      = (const float*)d_in[2];   // [P,4] center-size
    const float* truths    = (const float*)d_in[3];   // [B,O,4] point form
    const int*   labels    = (const int*)d_in[4];     // [B,O]
    float* out = (float*)d_out;

    // workspace carve-up (~2.3 MB)
    int* forced_p = (int*)d_ws;                                 // B*O
    float* negce  = (float*)(forced_p + B * O);                 // B*P
    int* num_pos  = (int*)(negce + (size_t)B * P);              // B
    float* possum = (float*)(num_pos + B);                      // B
    float* lossl  = possum + B;                                 // B
    float* acc    = lossl + B;                                  // 2
    int* done     = (int*)(acc + 2);                            // 1
    int* done_b   = done + 1;                                   // B

    bp_k<<<(B * O) / 4, 256, 0, stream>>>(dbox, truths, forced_p,
                                          num_pos, possum, lossl, acc, done, done_b);
    loss_mine_k<<<dim3(NBLK, B), 256, 0, stream>>>(
        loc_data, conf_data, dbox, truths, labels, forced_p,
        negce, num_pos, possum, lossl, acc, done, done_b, out);
}

// Round 3
// 365.778 us; speedup vs baseline: 1.9585x; 1.9585x over previous
//
#include <hip/hip_runtime.h>
#include <stdint.h>
#include <math.h>

#define B 64
#define P 8732
#define C 81
#define O 16
#define THRESH 0.5f
#define NEGPOS 3
#define VAR0 0.1f
#define VAR1 0.2f

// loss_k tiling: 4 waves/block, 16-lane groups, TWO rows per group per body.
// ITER=8 -> 64 consecutive rows per wave, 256 per block (2240 blocks total):
// halves block count vs ITER=4 to amortize prologue/epilogue; body unchanged.
#define ITER 8
#define ROWS_PER_WAVE (8 * ITER)           // 64
#define ROWS_PER_BLOCK (4 * ROWS_PER_WAVE) // 256

// ---------------------------------------------------------------------------
// K1: best prior per (b,o) + accumulator init. One wave per (b,o), 256 blocks
// x 256 threads. 4-way unrolled p-loop gives 4 independent float4 loads in
// flight per lane. Packed running-max key -> ties resolve to SMALLEST p
// (argmax first-occurrence).
// ---------------------------------------------------------------------------
__global__ __launch_bounds__(256) void bp_k(const float* __restrict__ dbox,
                                            const float* __restrict__ truths,
                                            int* __restrict__ forced_p,
                                            int* __restrict__ num_pos,
                                            float* __restrict__ possum,
                                            float* __restrict__ lossl,
                                            float* __restrict__ acc,
                                            int* __restrict__ done) {
    const int tid = threadIdx.x;
    if (blockIdx.x == 0) {                 // init for later kernels (stream order)
        if (tid < B) { num_pos[tid] = 0; possum[tid] = 0.f; lossl[tid] = 0.f; }
        if (tid == B) { acc[0] = 0.f; acc[1] = 0.f; }
        if (tid == B + 1) { *done = 0; }
    }
    const int lane = tid & 63;
    const int gw = blockIdx.x * 4 + (tid >> 6);     // 0..1023 = (b,o) pair
    const int b = gw >> 4, o = gw & 15;
    const float4 t = *(const float4*)(truths + (size_t)(b * O + o) * 4);
    const float ta = (t.z - t.x) * (t.w - t.y);

    unsigned long long best = 0ull;
    for (int p0 = lane; p0 < P; p0 += 256) {
#pragma unroll
        for (int u = 0; u < 4; ++u) {
            const int p = p0 + 64 * u;
            if (p < P) {
                const float4 db = *(const float4*)(dbox + (size_t)p * 4);
                const float px0 = db.x - db.z * 0.5f, py0 = db.y - db.w * 0.5f;
                const float px1 = db.x + db.z * 0.5f, py1 = db.y + db.w * 0.5f;
                const float parea = (px1 - px0) * (py1 - py0);
                float ix = fminf(t.z, px1) - fmaxf(t.x, px0);
                float iy = fminf(t.w, py1) - fmaxf(t.y, py0);
                ix = fmaxf(ix, 0.f); iy = fmaxf(iy, 0.f);
                const float inter = ix * iy;
                const float ov = inter / (ta + parea - inter);
                const unsigned long long key =
                    ((unsigned long long)__float_as_uint(ov) << 32) |
                    (unsigned long long)(0xFFFFFFFFu - (unsigned)p);
                if (key > best) best = key;
            }
        }
    }
    for (int off = 32; off; off >>= 1) {
        const unsigned long long o2 = __shfl_xor(best, off);
        if (o2 > best) best = o2;
    }
    if (lane == 0)
        forced_p[b * O + o] = (int)(0xFFFFFFFFu - (unsigned)(best & 0xFFFFFFFFull));
}

// ---------------------------------------------------------------------------
// K2: fused match + one-pass CE + smooth-L1. 16-lane groups, two rows per
// group per body. Conf row loaded as dwordx4 + dword + broadcast; forced-prior
// override via __ballot + __clz; picked logit via one __shfl from the holder
// lane. Plain stores to negce; kernel boundary provides coherence for mine_k
// (round-2 lesson: in-kernel device fences + scratch-spilled mining = 2x
// regression). One-pass CE is safe: logits ~ N(0,1).
// ---------------------------------------------------------------------------
__global__ __launch_bounds__(256) void loss_k(
        const float* __restrict__ loc_data,
        const float* __restrict__ conf_data,
        const float* __restrict__ dbox,
        const float* __restrict__ truths,
        const int* __restrict__ labels,
        const int* __restrict__ forced_p,
        float* __restrict__ negce,
        int* __restrict__ num_pos, float* __restrict__ possum,
        float* __restrict__ lossl) {
    const int b = blockIdx.y;
    const int tid = threadIdx.x;
    const int lane = tid & 63;
    const int wid = tid >> 6;             // 0..3
    const int sub = lane & 15;
    const int gbase = lane & 48;          // 16*group

    __shared__ float s_truth[O * 4];
    __shared__ float s_l, s_p;
    __shared__ int s_n;
    if (tid < O * 4) s_truth[tid] = truths[b * O * 4 + tid];
    if (tid == 0) { s_l = 0.f; s_p = 0.f; s_n = 0; }

    // per-lane registers: truth o=sub, forced prior o=sub, label o=sub
    const float4 tt = *(const float4*)(truths + (size_t)(b * O + sub) * 4);
    const int f_reg = forced_p[b * O + sub];
    const int lab_reg = labels[b * O + sub];
    const float tarea = (tt.z - tt.x) * (tt.w - tt.y);
    __syncthreads();

    float l_acc = 0.f;      // smooth-L1 partials
    float p_acc = 0.f;      // positive-CE partial
    int n_acc = 0;          // positive count partial

    const int wbase = blockIdx.x * ROWS_PER_BLOCK + wid * ROWS_PER_WAVE;

    for (int r = 0; r < ITER; ++r) {
        const int pA = wbase + 8 * r + (gbase >> 4);
        const int pB = pA + 4;
        const bool actA = (pA < P), actB = (pB < P);
        const int dA = actA ? pA : P - 1;
        const int dB = actB ? pB : P - 1;
        const size_t rowA = (size_t)b * P + dA;
        const size_t rowB = (size_t)b * P + dB;

        // ---- issue ALL loads for both rows up front (wide)
        const float* rpA = conf_data + rowA * C;
        const float* rpB = conf_data + rowB * C;
        const float4 qA = *(const float4*)(rpA + 4 * sub);   // floats 0..63
        const float4 qB = *(const float4*)(rpB + 4 * sub);
        const float eA = rpA[64 + sub];                      // floats 64..79
        const float eB = rpB[64 + sub];
        const float e80A = rpA[80];                          // broadcast
        const float e80B = rpB[80];
        const float4 dbA = *(const float4*)(dbox + (size_t)dA * 4);
        const float4 dbB = *(const float4*)(dbox + (size_t)dB * 4);

        // ---- IoU + 16-lane argmax for A and B (chains interleave)
        float ovA, ovB;
        int tiA = sub, tiB = sub;
        {
            const float pax0 = dbA.x - dbA.z * 0.5f, pay0 = dbA.y - dbA.w * 0.5f;
            const float pax1 = dbA.x + dbA.z * 0.5f, pay1 = dbA.y + dbA.w * 0.5f;
            const float pareaA = (pax1 - pax0) * (pay1 - pay0);
            float ixA = fminf(tt.z, pax1) - fmaxf(tt.x, pax0);
            float iyA = fminf(tt.w, pay1) - fmaxf(tt.y, pay0);
            ixA = fmaxf(ixA, 0.f); iyA = fmaxf(iyA, 0.f);
            const float interA = ixA * iyA;
            ovA = interA / (tarea + pareaA - interA);

            const float pbx0 = dbB.x - dbB.z * 0.5f, pby0 = dbB.y - dbB.w * 0.5f;
            const float pbx1 = dbB.x + dbB.z * 0.5f, pby1 = dbB.y + dbB.w * 0.5f;
            const float pareaB = (pbx1 - pbx0) * (pby1 - pby0);
            float ixB = fminf(tt.z, pbx1) - fmaxf(tt.x, pbx0);
            float iyB = fminf(tt.w, pby1) - fmaxf(tt.y, pby0);
            ixB = fmaxf(ixB, 0.f); iyB = fmaxf(iyB, 0.f);
            const float interB = ixB * iyB;
            ovB = interB / (tarea + pareaB - interB);
        }
        for (int off = 8; off; off >>= 1) {
            const float oA = __shfl_xor(ovA, off);
            const int iA = __shfl_xor(tiA, off);
            const float oB = __shfl_xor(ovB, off);
            const int iB = __shfl_xor(tiB, off);
            if (oA > ovA || (oA == ovA && iA < tiA)) { ovA = oA; tiA = iA; }
            if (oB > ovB || (oB == ovB && iB < tiB)) { ovB = oB; tiB = iB; }
        }
        // ---- forced override via ballot (ascending o => highest set bit wins)
        const unsigned long long balA = __ballot(f_reg == pA);
        const unsigned long long balB = __ballot(f_reg == pB);
        const unsigned mA = (unsigned)(balA >> gbase) & 0xFFFFu;
        const unsigned mB = (unsigned)(balB >> gbase) & 0xFFFFu;
        const bool fA = (mA != 0), fB = (mB != 0);
        if (fA) tiA = 31 - __clz(mA);
        if (fB) tiB = 31 - __clz(mB);
        const int labA = __shfl(lab_reg, gbase | tiA);
        const int labB = __shfl(lab_reg, gbase | tiB);
        const int confA = (fA || ovA >= THRESH) ? (labA + 1) : 0;
        const int confB = (fB || ovB >= THRESH) ? (labB + 1) : 0;
        const bool posA = confA > 0, posB = confB > 0;

        // ---- one-pass CE, both rows interleaved
        float sA = __expf(qA.x) + __expf(qA.y) + __expf(qA.z) + __expf(qA.w) + __expf(eA);
        float sB = __expf(qB.x) + __expf(qB.y) + __expf(qB.z) + __expf(qB.w) + __expf(eB);
        for (int off = 8; off; off >>= 1) {
            sA += __shfl_xor(sA, off);
            sB += __shfl_xor(sB, off);
        }
        sA += __expf(e80A);
        sB += __expf(e80B);

        // picked logit: fetch from holder lane with one shuffle
        const float selA = (confA < 64)
            ? ((confA & 2) ? ((confA & 1) ? qA.w : qA.z) : ((confA & 1) ? qA.y : qA.x))
            : eA;
        const float selB = (confB < 64)
            ? ((confB & 2) ? ((confB & 1) ? qB.w : qB.z) : ((confB & 1) ? qB.y : qB.x))
            : eB;
        const int hA = (confA < 64) ? (confA >> 2) : (confA & 15);
        const int hB = (confB < 64) ? (confB >> 2) : (confB & 15);
        float pkA = __shfl(selA, gbase | hA);
        float pkB = __shfl(selB, gbase | hB);
        if (confA == 80) pkA = e80A;
        if (confB == 80) pkB = e80B;

        const float cevA = __logf(sA) - pkA;
        const float cevB = __logf(sB) - pkB;

        if (actA && sub == 0) {
            negce[rowA] = posA ? 0.f : cevA;
            if (posA) { p_acc += cevA; n_acc++; }
        }
        if (actB && sub == 0) {
            negce[rowB] = posB ? 0.f : cevB;
            if (posB) { p_acc += cevB; n_acc++; }
        }
        // ---- smooth-L1: lanes sub<4 handle one component each
        if (actA && posA && sub < 4) {
            const float mx0 = s_truth[tiA * 4 + 0], my0 = s_truth[tiA * 4 + 1];
            const float mx1 = s_truth[tiA * 4 + 2], my1 = s_truth[tiA * 4 + 3];
            float tgt;
            if (sub == 0)      tgt = ((mx0 + mx1) * 0.5f - dbA.x) / (VAR0 * dbA.z);
            else if (sub == 1) tgt = ((my0 + my1) * 0.5f - dbA.y) / (VAR0 * dbA.w);
            else if (sub == 2) tgt = logf((mx1 - mx0) / dbA.z) / VAR1;
            else               tgt = logf((my1 - my0) / dbA.w) / VAR1;
            const float d = fabsf(loc_data[rowA * 4 + sub] - tgt);
            l_acc += (d < 1.f) ? 0.5f * d * d : d - 0.5f;
        }
        if (actB && posB && sub < 4) {
            const float mx0 = s_truth[tiB * 4 + 0], my0 = s_truth[tiB * 4 + 1];
            const float mx1 = s_truth[tiB * 4 + 2], my1 = s_truth[tiB * 4 + 3];
            float tgt;
            if (sub == 0)      tgt = ((mx0 + mx1) * 0.5f - dbB.x) / (VAR0 * dbB.z);
            else if (sub == 1) tgt = ((my0 + my1) * 0.5f - dbB.y) / (VAR0 * dbB.w);
            else if (sub == 2) tgt = logf((mx1 - mx0) / dbB.z) / VAR1;
            else               tgt = logf((my1 - my0) / dbB.w) / VAR1;
            const float d = fabsf(loc_data[rowB * 4 + sub] - tgt);
            l_acc += (d < 1.f) ? 0.5f * d * d : d - 0.5f;
        }
    }
    // wave reduction of partials, then block, then global
    for (int off = 32; off; off >>= 1) {
        l_acc += __shfl_xor(l_acc, off);
        p_acc += __shfl_xor(p_acc, off);
        n_acc += __shfl_xor(n_acc, off);
    }
    if (lane == 0) {
        atomicAdd(&s_l, l_acc);
        atomicAdd(&s_p, p_acc);
        atomicAdd(&s_n, n_acc);
    }
    __syncthreads();
    if (tid == 0) {
        atomicAdd(&lossl[b], s_l);
        atomicAdd(&possum[b], s_p);
        atomicAdd(&num_pos[b], s_n);
    }
}

// ---------------------------------------------------------------------------
// K3: hard-negative mining (row in registers, bit binary search, tie-exact)
// + last-block finalize via device-scope atomics. (proven round-1 version)
// ---------------------------------------------------------------------------
__global__ __launch_bounds__(1024) void mine_k(
        const float* __restrict__ negce,
        const int* __restrict__ num_pos,
        const float* __restrict__ possum,
        const float* __restrict__ lossl,
        float* __restrict__ acc, int* __restrict__ done,
        float* __restrict__ out) {
    const int b = blockIdx.x;
    const int tid = threadIdx.x;
    const int lane = tid & 63;
    const int wid = tid >> 6;          // 0..15
    const float* x = negce + (size_t)b * P;
    float v[9];
#pragma unroll
    for (int j = 0; j < 9; ++j) {
        const int i = tid + j * 1024;
        v[j] = (i < P) ? x[i] : -1.0f;
    }
    int k = num_pos[b] * NEGPOS;
    if (k > P) k = P;

    __shared__ int wred[2][16];
    __shared__ float wsumf[16];
    __shared__ int wcnt[16];
    float S = 0.f;
    if (k > 0) {
        unsigned lo = 0u, hi = 0x7F800000u;
        int parity = 0;
        while (lo < hi) {
            const unsigned mid = lo + ((hi - lo) >> 1);
            const float t = __uint_as_float(mid);
            int cnt = 0;
#pragma unroll
            for (int j = 0; j < 9; ++j) cnt += (v[j] > t) ? 1 : 0;
            for (int off = 32; off; off >>= 1) cnt += __shfl_xor(cnt, off);
            if (lane == 0) wred[parity][wid] = cnt;
            __syncthreads();
            int total = 0;
#pragma unroll
            for (int w = 0; w < 16; ++w) total += wred[parity][w];
            if (total < k) hi = mid; else lo = mid + 1;
            parity ^= 1;
        }
        const float t = __uint_as_float(lo);   // k-th largest
        float sum = 0.f;
        int cnt = 0;
#pragma unroll
        for (int j = 0; j < 9; ++j) {
            if (v[j] > t) { sum += v[j]; cnt++; }
        }
        for (int off = 32; off; off >>= 1) {
            sum += __shfl_xor(sum, off);
            cnt += __shfl_xor(cnt, off);
        }
        if (lane == 0) { wsumf[wid] = sum; wcnt[wid] = cnt; }
        __syncthreads();
        if (tid == 0) {
            float ts = 0.f; int tc = 0;
#pragma unroll
            for (int w = 0; w < 16; ++w) { ts += wsumf[w]; tc += wcnt[w]; }
            S = ts + (float)(k - tc) * t;
        }
    }
    if (tid == 0) {
        atomicAdd(&acc[1], possum[b] + S);
        __threadfence();
        const int prev = atomicAdd(done, 1);
        if (prev == B - 1) {               // last block finalizes
            __threadfence();
            float N = 0.f, L = 0.f;
            for (int i = 0; i < B; ++i) { N += (float)num_pos[i]; L += lossl[i]; }
            const float cval = atomicAdd(&acc[1], 0.0f);  // device-coherent read
            out[0] = L / N;
            out[1] = cval / N;
        }
    }
}

extern "C" void kernel_launch(void* const* d_in, const int* in_sizes, int n_in,
                              void* d_out, int out_size, void* d_ws, size_t ws_size,
                              hipStream_t stream) {
    (void)in_sizes; (void)n_in; (void)out_size; (void)ws_size;
    const float* loc_data  = (const float*)d_in[0];   // [B,P,4]
    const float* conf_data = (const float*)d_in[1];   // [B,P,C]
    const float* dbox      = (const float*)d_in[2];   // [P,4] center-size
    const float* truths    = (const float*)d_in[3];   // [B,O,4] point form
    const int*   labels    = (const int*)d_in[4];     // [B,O]
    float* out = (float*)d_out;

    // workspace carve-up (~2.3 MB)
    int* forced_p = (int*)d_ws;                                 // B*O
    float* negce  = (float*)(forced_p + B * O);                 // B*P
    int* num_pos  = (int*)(negce + (size_t)B * P);              // B
    float* possum = (float*)(num_pos + B);                      // B
    float* lossl  = possum + B;                                 // B
    float* acc    = lossl + B;                                  // 2
    int* done     = (int*)(acc + 2);                            // 1

    bp_k<<<(B * O) / 4, 256, 0, stream>>>(dbox, truths, forced_p,
                                          num_pos, possum, lossl, acc, done);
    loss_k<<<dim3((P + ROWS_PER_BLOCK - 1) / ROWS_PER_BLOCK, B), 256, 0, stream>>>(
        loc_data, conf_data, dbox, truths, labels, forced_p,
        negce, num_pos, possum, lossl);
    mine_k<<<B, 1024, 0, stream>>>(negce, num_pos, possum, lossl, acc, done, out);
}